// Round 1
// baseline (3971.902 us; speedup 1.0000x reference)
//
#include <hip/hip_runtime.h>
#include <hip/hip_bf16.h>

#define CDIM 256
#define NSEQ 128
#define HID 1024
#define RB 16           // rows per block in y_mega
#define EPS 1e-5f
#define SCALE 0.17677669529663687f   // 1/sqrt(32)

// ---------------------------------------------------------------------------
// per-row LN stats over RB rows stored in LDS (row stride `stride`, 256 cols)
// wave w handles rows w, w+4, w+8, w+12
__device__ __forceinline__ void row_ln_stats(const float* buf, int stride,
                                             float* sMu, float* sRs) {
    const int wave = threadIdx.x >> 6;
    const int lane = threadIdx.x & 63;
    for (int r = wave; r < RB; r += 4) {
        const float* p = buf + r * stride;
        float s = 0.f, ss = 0.f;
        #pragma unroll
        for (int m = 0; m < 4; ++m) {
            float v = p[lane + 64 * m];
            s += v; ss += v * v;
        }
        #pragma unroll
        for (int off = 32; off; off >>= 1) {
            s  += __shfl_xor(s, off);
            ss += __shfl_xor(ss, off);
        }
        if (lane == 0) {
            float mu = s * (1.f / 256.f);
            sMu[r] = mu;
            sRs[r] = rsqrtf(ss * (1.f / 256.f) - mu * mu + EPS);
        }
    }
}

// block-wide LN over 256 threads (one value per thread); returns (mu, rstd)
__device__ __forceinline__ float2 block_ln(float val, float* sred) {
    const int wave = threadIdx.x >> 6;
    const int lane = threadIdx.x & 63;
    float s = val, ss = val * val;
    #pragma unroll
    for (int off = 32; off; off >>= 1) {
        s  += __shfl_xor(s, off);
        ss += __shfl_xor(ss, off);
    }
    __syncthreads();                       // protect sred from previous use
    if (lane == 0) { sred[wave] = s; sred[4 + wave] = ss; }
    __syncthreads();
    s  = sred[0] + sred[1] + sred[2] + sred[3];
    ss = sred[4] + sred[5] + sred[6] + sred[7];
    float mu = s * (1.f / 256.f);
    float rs = rsqrtf(ss * (1.f / 256.f) - mu * mu + EPS);
    return make_float2(mu, rs);
}

// ---------------------------------------------------------------------------
// x1 = LN(x, ln1)
__global__ __launch_bounds__(256) void ln1_kernel(
    const float* __restrict__ x, const float* __restrict__ s,
    const float* __restrict__ b, float* __restrict__ x1) {
    __shared__ float sred[8];
    const int bi = blockIdx.x, t = threadIdx.x;
    float v = x[bi * CDIM + t];
    float2 mr = block_ln(v, sred);
    x1[bi * CDIM + t] = (v - mr.x) * mr.y * s[t] + b[t];
}

// q,k,v = x1 @ W{q,k,v} + b  (one row per block)
__global__ __launch_bounds__(256) void qkv_kernel(
    const float* __restrict__ x1,
    const float* __restrict__ Wq, const float* __restrict__ bq,
    const float* __restrict__ Wk, const float* __restrict__ bk,
    const float* __restrict__ Wv, const float* __restrict__ bv,
    float* __restrict__ q, float* __restrict__ k, float* __restrict__ v) {
    __shared__ float sX[CDIM];
    const int bi = blockIdx.x, t = threadIdx.x;
    sX[t] = x1[bi * CDIM + t];
    __syncthreads();
    float aq = bq[t], ak = bk[t], av = bv[t];
    for (int kk = 0; kk < CDIM; kk += 4) {
        float4 xv = *(const float4*)&sX[kk];
        #pragma unroll
        for (int d = 0; d < 4; ++d) {
            float xd = (d == 0) ? xv.x : (d == 1) ? xv.y : (d == 2) ? xv.z : xv.w;
            aq += xd * Wq[(kk + d) * CDIM + t];
            ak += xd * Wk[(kk + d) * CDIM + t];
            av += xd * Wv[(kk + d) * CDIM + t];
        }
    }
    q[bi * CDIM + t] = aq;
    k[bi * CDIM + t] = ak;
    v[bi * CDIM + t] = av;
}

// ---------------------------------------------------------------------------
// Fused edge pipeline over RB=16 rows of the flattened (b,i,j) dim:
//   e = y@We+be ; attn = q*k*scale*(e+1)*e  (-> ws for softmax)
//   edge = attn@Woe+boe ; y2 = LN(edge + y, ln4)
//   h = relu(y2@w1+b1) ; out = h@w2+b2 ; y_out = LN(y2 + out, ln6)
// Thread (ty,tx): ty = tid>>7 owns rows ty*8..ty*8+7, cols tx and tx+128.
__global__ __launch_bounds__(256) void y_mega(
    const float* __restrict__ y,  const float* __restrict__ qg,
    const float* __restrict__ kg,
    const float* __restrict__ We, const float* __restrict__ be,
    const float* __restrict__ Woe,const float* __restrict__ boe,
    const float* __restrict__ w1, const float* __restrict__ b1,
    const float* __restrict__ w2, const float* __restrict__ b2,
    const float* __restrict__ ln4s, const float* __restrict__ ln4b,
    const float* __restrict__ ln6s, const float* __restrict__ ln6b,
    float* __restrict__ attn_out, float* __restrict__ yout) {
    __shared__ float sY[RB][CDIM];     // 16 KiB: y tile
    __shared__ float sA[RB][CDIM];     // 16 KiB: attn -> preLN -> y2
    __shared__ float sH[RB][512];      // 32 KiB: hid half -> preLN staging
    __shared__ float sMu[RB], sRs[RB];

    const int tid = threadIdx.x;
    const int tx  = tid & 127;
    const int ty  = tid >> 7;
    const int c0  = tx, c1 = tx + 128;
    const int rb  = ty * 8;
    const long long row0 = (long long)blockIdx.x * RB;

    for (int r = 0; r < RB; ++r)
        sY[r][tid] = y[(row0 + r) * CDIM + tid];
    __syncthreads();

    // ---- P1: e = y@We + be -------------------------------------------------
    float a0[8], a1[8];
    #pragma unroll
    for (int r = 0; r < 8; ++r) { a0[r] = be[c0]; a1[r] = be[c1]; }
    for (int kk = 0; kk < CDIM; kk += 4) {
        float wa0 = We[(kk + 0) * CDIM + c0], wb0 = We[(kk + 0) * CDIM + c1];
        float wa1 = We[(kk + 1) * CDIM + c0], wb1 = We[(kk + 1) * CDIM + c1];
        float wa2 = We[(kk + 2) * CDIM + c0], wb2 = We[(kk + 2) * CDIM + c1];
        float wa3 = We[(kk + 3) * CDIM + c0], wb3 = We[(kk + 3) * CDIM + c1];
        #pragma unroll
        for (int r = 0; r < 8; ++r) {
            float4 yv = *(const float4*)&sY[rb + r][kk];
            a0[r] += yv.x * wa0 + yv.y * wa1 + yv.z * wa2 + yv.w * wa3;
            a1[r] += yv.x * wb0 + yv.y * wb1 + yv.z * wb2 + yv.w * wb3;
        }
    }
    // attn = q*k*scale*(e+1)*e  -> sA and ws
    #pragma unroll
    for (int r = 0; r < 8; ++r) {
        long long gr = row0 + rb + r;
        int b = (int)(gr >> 14);
        int i = (int)((gr >> 7) & 127);
        int j = (int)(gr & 127);
        const float* qrow = qg + ((b << 7) + i) * CDIM;
        const float* krow = kg + ((b << 7) + j) * CDIM;
        float e0 = a0[r], e1 = a1[r];
        float t0 = qrow[c0] * krow[c0] * SCALE * ((e0 + 1.f) * e0);
        float t1 = qrow[c1] * krow[c1] * SCALE * ((e1 + 1.f) * e1);
        sA[rb + r][c0] = t0;  sA[rb + r][c1] = t1;
        attn_out[gr * CDIM + c0] = t0;
        attn_out[gr * CDIM + c1] = t1;
    }
    __syncthreads();

    // ---- P2: edge = attn@Woe + boe ----------------------------------------
    #pragma unroll
    for (int r = 0; r < 8; ++r) { a0[r] = boe[c0]; a1[r] = boe[c1]; }
    for (int kk = 0; kk < CDIM; kk += 4) {
        float wa0 = Woe[(kk + 0) * CDIM + c0], wb0 = Woe[(kk + 0) * CDIM + c1];
        float wa1 = Woe[(kk + 1) * CDIM + c0], wb1 = Woe[(kk + 1) * CDIM + c1];
        float wa2 = Woe[(kk + 2) * CDIM + c0], wb2 = Woe[(kk + 2) * CDIM + c1];
        float wa3 = Woe[(kk + 3) * CDIM + c0], wb3 = Woe[(kk + 3) * CDIM + c1];
        #pragma unroll
        for (int r = 0; r < 8; ++r) {
            float4 av = *(const float4*)&sA[rb + r][kk];
            a0[r] += av.x * wa0 + av.y * wa1 + av.z * wa2 + av.w * wa3;
            a1[r] += av.x * wb0 + av.y * wb1 + av.z * wb2 + av.w * wb3;
        }
    }
    // preLN y2 = edge + y
    float p0[8], p1[8];
    #pragma unroll
    for (int r = 0; r < 8; ++r) {
        p0[r] = a0[r] + sY[rb + r][c0];
        p1[r] = a1[r] + sY[rb + r][c1];
    }
    __syncthreads();                    // all reads of sA (attn) done
    #pragma unroll
    for (int r = 0; r < 8; ++r) { sA[rb + r][c0] = p0[r]; sA[rb + r][c1] = p1[r]; }
    __syncthreads();
    row_ln_stats(&sA[0][0], CDIM, sMu, sRs);
    __syncthreads();
    float y2v0[8], y2v1[8];
    #pragma unroll
    for (int r = 0; r < 8; ++r) {
        float mu = sMu[rb + r], rs = sRs[rb + r];
        y2v0[r] = (p0[r] - mu) * rs * ln4s[c0] + ln4b[c0];
        y2v1[r] = (p1[r] - mu) * rs * ln4s[c1] + ln4b[c1];
        sA[rb + r][c0] = y2v0[r];
        sA[rb + r][c1] = y2v1[r];
    }
    __syncthreads();                    // sA now holds normalized y2

    // ---- P3: MLP (hidden in halves of 512, kept in LDS) --------------------
    float o0[8], o1[8];
    #pragma unroll
    for (int r = 0; r < 8; ++r) { o0[r] = b2[c0]; o1[r] = b2[c1]; }
    for (int half = 0; half < 2; ++half) {
        float h[8][4];
        #pragma unroll
        for (int m = 0; m < 4; ++m) {
            float bv = b1[half * 512 + tx + 128 * m];
            #pragma unroll
            for (int r = 0; r < 8; ++r) h[r][m] = bv;
        }
        for (int kk = 0; kk < CDIM; kk += 4) {
            float w[4][4];
            #pragma unroll
            for (int d = 0; d < 4; ++d)
                #pragma unroll
                for (int m = 0; m < 4; ++m)
                    w[d][m] = w1[(kk + d) * HID + half * 512 + tx + 128 * m];
            #pragma unroll
            for (int r = 0; r < 8; ++r) {
                float4 xv = *(const float4*)&sA[rb + r][kk];
                #pragma unroll
                for (int m = 0; m < 4; ++m)
                    h[r][m] += xv.x * w[0][m] + xv.y * w[1][m]
                             + xv.z * w[2][m] + xv.w * w[3][m];
            }
        }
        #pragma unroll
        for (int r = 0; r < 8; ++r)
            #pragma unroll
            for (int m = 0; m < 4; ++m)
                sH[rb + r][tx + 128 * m] = fmaxf(h[r][m], 0.f);
        __syncthreads();
        for (int uu = 0; uu < 512; uu += 4) {
            float wa[4], wb[4];
            #pragma unroll
            for (int d = 0; d < 4; ++d) {
                wa[d] = w2[(half * 512 + uu + d) * CDIM + c0];
                wb[d] = w2[(half * 512 + uu + d) * CDIM + c1];
            }
            #pragma unroll
            for (int r = 0; r < 8; ++r) {
                float4 hv = *(const float4*)&sH[rb + r][uu];
                o0[r] += hv.x * wa[0] + hv.y * wa[1] + hv.z * wa[2] + hv.w * wa[3];
                o1[r] += hv.x * wb[0] + hv.y * wb[1] + hv.z * wb[2] + hv.w * wb[3];
            }
        }
        __syncthreads();                // before sH reuse
    }

    // ---- P4: y_out = LN(y2 + mlp_out, ln6) --------------------------------
    #pragma unroll
    for (int r = 0; r < 8; ++r) {
        p0[r] = y2v0[r] + o0[r];
        p1[r] = y2v1[r] + o1[r];
        sH[rb + r][c0] = p0[r];
        sH[rb + r][c1] = p1[r];
    }
    __syncthreads();
    row_ln_stats(&sH[0][0], 512, sMu, sRs);
    __syncthreads();
    #pragma unroll
    for (int r = 0; r < 8; ++r) {
        long long gr = row0 + rb + r;
        float mu = sMu[rb + r], rs = sRs[rb + r];
        yout[gr * CDIM + c0] = (p0[r] - mu) * rs * ln6s[c0] + ln6b[c0];
        yout[gr * CDIM + c1] = (p1[r] - mu) * rs * ln6s[c1] + ln6b[c1];
    }
}

// ---------------------------------------------------------------------------
// softmax over j (per b,i,channel) + weighted sum of v
__global__ __launch_bounds__(256) void softmax_agg(
    const float* __restrict__ attn, const float* __restrict__ v,
    float* __restrict__ agg) {
    const int bi = blockIdx.x, t = threadIdx.x;
    const float* ap = attn + (long long)bi * NSEQ * CDIM + t;
    const float* vp = v + (long long)(bi >> 7) * NSEQ * CDIM + t;
    float m = -1e30f;
    for (int j = 0; j < NSEQ; ++j) m = fmaxf(m, ap[j * CDIM]);
    float s = 0.f, o = 0.f;
    for (int j = 0; j < NSEQ; ++j) {
        float ex = __expf(ap[j * CDIM] - m);
        s += ex;
        o += ex * vp[j * CDIM];
    }
    agg[bi * CDIM + t] = o / s;
}

// ---------------------------------------------------------------------------
// node_out = agg@Won+bon ; x2 = LN(x1+node_out) ; mlp ; x_out = LN(x2+mlp)
__global__ __launch_bounds__(256) void x_path(
    const float* __restrict__ x1, const float* __restrict__ agg,
    const float* __restrict__ Won, const float* __restrict__ bon,
    const float* __restrict__ ln3s, const float* __restrict__ ln3b,
    const float* __restrict__ w1, const float* __restrict__ b1,
    const float* __restrict__ w2, const float* __restrict__ b2,
    const float* __restrict__ ln5s, const float* __restrict__ ln5b,
    float* __restrict__ xout) {
    __shared__ float sG[CDIM];
    __shared__ float sX2[CDIM];
    __shared__ float sH[HID];
    __shared__ float sred[8];
    const int bi = blockIdx.x, t = threadIdx.x;
    sG[t] = agg[bi * CDIM + t];
    __syncthreads();
    float no = bon[t];
    for (int kk = 0; kk < CDIM; kk += 4) {
        float4 gv = *(const float4*)&sG[kk];
        no += gv.x * Won[(kk + 0) * CDIM + t] + gv.y * Won[(kk + 1) * CDIM + t]
            + gv.z * Won[(kk + 2) * CDIM + t] + gv.w * Won[(kk + 3) * CDIM + t];
    }
    float pre = x1[bi * CDIM + t] + no;
    float2 mr = block_ln(pre, sred);
    float x2 = (pre - mr.x) * mr.y * ln3s[t] + ln3b[t];
    sX2[t] = x2;
    __syncthreads();
    float h[4];
    #pragma unroll
    for (int m = 0; m < 4; ++m) h[m] = b1[t + 256 * m];
    for (int kk = 0; kk < CDIM; kk += 4) {
        float4 xv = *(const float4*)&sX2[kk];
        #pragma unroll
        for (int m = 0; m < 4; ++m) {
            int u = t + 256 * m;
            h[m] += xv.x * w1[(kk + 0) * HID + u] + xv.y * w1[(kk + 1) * HID + u]
                  + xv.z * w1[(kk + 2) * HID + u] + xv.w * w1[(kk + 3) * HID + u];
        }
    }
    #pragma unroll
    for (int m = 0; m < 4; ++m) sH[t + 256 * m] = fmaxf(h[m], 0.f);
    __syncthreads();
    float o = b2[t];
    for (int u = 0; u < HID; u += 4) {
        float4 hv = *(const float4*)&sH[u];
        o += hv.x * w2[(u + 0) * CDIM + t] + hv.y * w2[(u + 1) * CDIM + t]
           + hv.z * w2[(u + 2) * CDIM + t] + hv.w * w2[(u + 3) * CDIM + t];
    }
    float pre2 = x2 + o;
    float2 mr2 = block_ln(pre2, sred);
    xout[bi * CDIM + t] = (pre2 - mr2.x) * mr2.y * ln5s[t] + ln5b[t];
}

// ---------------------------------------------------------------------------
extern "C" void kernel_launch(void* const* d_in, const int* in_sizes, int n_in,
                              void* d_out, int out_size, void* d_ws, size_t ws_size,
                              hipStream_t stream) {
    const float* x   = (const float*)d_in[0];
    const float* y   = (const float*)d_in[1];
    const float* Wq  = (const float*)d_in[2];  const float* bq  = (const float*)d_in[3];
    const float* Wk  = (const float*)d_in[4];  const float* bk  = (const float*)d_in[5];
    const float* Wv  = (const float*)d_in[6];  const float* bv  = (const float*)d_in[7];
    const float* We  = (const float*)d_in[8];  const float* be  = (const float*)d_in[9];
    const float* Woe = (const float*)d_in[10]; const float* boe = (const float*)d_in[11];
    const float* Won = (const float*)d_in[12]; const float* bon = (const float*)d_in[13];
    const float* m1w1= (const float*)d_in[14]; const float* m1b1= (const float*)d_in[15];
    const float* m1w2= (const float*)d_in[16]; const float* m1b2= (const float*)d_in[17];
    const float* m2w1= (const float*)d_in[18]; const float* m2b1= (const float*)d_in[19];
    const float* m2w2= (const float*)d_in[20]; const float* m2b2= (const float*)d_in[21];
    const float* ln1s= (const float*)d_in[22]; const float* ln1b= (const float*)d_in[23];
    const float* ln3s= (const float*)d_in[24]; const float* ln3b= (const float*)d_in[25];
    const float* ln4s= (const float*)d_in[26]; const float* ln4b= (const float*)d_in[27];
    const float* ln5s= (const float*)d_in[28]; const float* ln5b= (const float*)d_in[29];
    const float* ln6s= (const float*)d_in[30]; const float* ln6b= (const float*)d_in[31];

    const int BN  = 8 * 128;            // 1024 node rows
    const int BNN = 8 * 128 * 128;      // 131072 edge rows

    float* ws   = (float*)d_ws;
    float* x1   = ws;                   // 262144
    float* q    = x1  + BN * CDIM;      // 262144
    float* k    = q   + BN * CDIM;      // 262144
    float* v    = k   + BN * CDIM;      // 262144
    float* agg  = v   + BN * CDIM;      // 262144
    float* attn = agg + BN * CDIM;      // 33554432  (total ~139.5 MB)

    float* xout = (float*)d_out;
    float* yout = xout + BN * CDIM;

    ln1_kernel<<<BN, 256, 0, stream>>>(x, ln1s, ln1b, x1);
    qkv_kernel<<<BN, 256, 0, stream>>>(x1, Wq, bq, Wk, bk, Wv, bv, q, k, v);
    y_mega<<<BNN / RB, 256, 0, stream>>>(y, q, k, We, be, Woe, boe,
                                         m2w1, m2b1, m2w2, m2b2,
                                         ln4s, ln4b, ln6s, ln6b, attn, yout);
    softmax_agg<<<BN, 256, 0, stream>>>(attn, v, agg);
    x_path<<<BN, 256, 0, stream>>>(x1, agg, Won, bon, ln3s, ln3b,
                                   m1w1, m1b1, m1w2, m1b2, ln5s, ln5b, xout);
}

// Round 2
// 991.864 us; speedup vs baseline: 4.0045x; 4.0045x over previous
//
#include <hip/hip_runtime.h>

#define CDIM 256
#define NSEQ 128
#define HID 1024
#define EPS 1e-5f
#define SCALE 0.17677669529663687f   // 1/sqrt(32)
#define ASTR 264                     // A-plane row stride (elements): 16B-aligned + bank spread
#define MROWS 64

typedef __attribute__((ext_vector_type(8))) short short8;
typedef __attribute__((ext_vector_type(4))) float f32x4;

static __device__ __forceinline__ unsigned short f2bf(float x) {
    unsigned u = __float_as_uint(x);
    u += 0x7fff + ((u >> 16) & 1);          // RNE
    return (unsigned short)(u >> 16);
}
static __device__ __forceinline__ float bf2f(unsigned short h) {
    return __uint_as_float(((unsigned)h) << 16);
}

// ---------------------------------------------------------------------------
// Split W (K x N fp32, row-major) into hi/lo bf16, swizzled into MFMA
// B-fragment order: out[((nt*(K/32)+ks)*64+lane)*8+j] = W[ks*32+(lane>>4)*8+j][nt*16+(lane&15)]
__global__ __launch_bounds__(256) void prep_w(const float* __restrict__ W,
        unsigned short* __restrict__ hi, unsigned short* __restrict__ lo,
        int N, int ksBits) {
    int idx = blockIdx.x * 256 + threadIdx.x;
    int j = idx & 7, lane = (idx >> 3) & 63, rest = idx >> 9;
    int ks = rest & ((1 << ksBits) - 1), nt = rest >> ksBits;
    int n = nt * 16 + (lane & 15);
    int kk = ks * 32 + ((lane >> 4) << 3) + j;
    float x = W[kk * N + n];
    unsigned short h = f2bf(x);
    hi[idx] = h;
    lo[idx] = f2bf(x - bf2f(h));
}

// ---------------------------------------------------------------------------
// block-wide LN over 256 threads (one value per thread)
__device__ __forceinline__ float2 block_ln(float val, float* sred) {
    const int wave = threadIdx.x >> 6;
    const int lane = threadIdx.x & 63;
    float s = val, ss = val * val;
    #pragma unroll
    for (int off = 32; off; off >>= 1) {
        s  += __shfl_xor(s, off);
        ss += __shfl_xor(ss, off);
    }
    __syncthreads();
    if (lane == 0) { sred[wave] = s; sred[4 + wave] = ss; }
    __syncthreads();
    s  = sred[0] + sred[1] + sred[2] + sred[3];
    ss = sred[4] + sred[5] + sred[6] + sred[7];
    float mu = s * (1.f / 256.f);
    float rs = rsqrtf(ss * (1.f / 256.f) - mu * mu + EPS);
    return make_float2(mu, rs);
}

__global__ __launch_bounds__(256) void ln1_kernel(
    const float* __restrict__ x, const float* __restrict__ s,
    const float* __restrict__ b, float* __restrict__ x1) {
    __shared__ float sred[8];
    const int bi = blockIdx.x, t = threadIdx.x;
    float v = x[bi * CDIM + t];
    float2 mr = block_ln(v, sred);
    x1[bi * CDIM + t] = (v - mr.x) * mr.y * s[t] + b[t];
}

__global__ __launch_bounds__(256) void qkv_kernel(
    const float* __restrict__ x1,
    const float* __restrict__ Wq, const float* __restrict__ bq,
    const float* __restrict__ Wk, const float* __restrict__ bk,
    const float* __restrict__ Wv, const float* __restrict__ bv,
    float* __restrict__ q, float* __restrict__ k, float* __restrict__ v) {
    __shared__ float sX[CDIM];
    const int bi = blockIdx.x, t = threadIdx.x;
    sX[t] = x1[bi * CDIM + t];
    __syncthreads();
    float aq = bq[t], ak = bk[t], av = bv[t];
    for (int kk = 0; kk < CDIM; kk += 4) {
        float4 xv = *(const float4*)&sX[kk];
        #pragma unroll
        for (int d = 0; d < 4; ++d) {
            float xd = (d == 0) ? xv.x : (d == 1) ? xv.y : (d == 2) ? xv.z : xv.w;
            aq += xd * Wq[(kk + d) * CDIM + t];
            ak += xd * Wk[(kk + d) * CDIM + t];
            av += xd * Wv[(kk + d) * CDIM + t];
        }
    }
    q[bi * CDIM + t] = aq;
    k[bi * CDIM + t] = ak;
    v[bi * CDIM + t] = av;
}

// ---------------------------------------------------------------------------
// bf16x3 GEMM step: acc[mt][nt] += A*B with A = hi+lo LDS planes (K=256 per call),
// B = hi/lo swizzled global. 8 k-steps of 16x16x32.
static __device__ __forceinline__ void gemm16(
    const unsigned short* __restrict__ Ah, const unsigned short* __restrict__ Al,
    const unsigned short* __restrict__ Bh, const unsigned short* __restrict__ Bl,
    int nt0, int ksTotal, int ks0, int lane, f32x4 acc[4][2])
{
    const int l16 = lane & 15, quad = lane >> 4;
    #pragma unroll 2
    for (int ks = 0; ks < 8; ++ks) {
        short8 bh[2], bl[2];
        #pragma unroll
        for (int nt = 0; nt < 2; ++nt) {
            size_t off = ((size_t)((nt0 + nt) * ksTotal + (ks0 + ks)) * 64 + lane) * 8;
            bh[nt] = *(const short8*)(Bh + off);
            bl[nt] = *(const short8*)(Bl + off);
        }
        #pragma unroll
        for (int mt = 0; mt < 4; ++mt) {
            int ao = (mt * 16 + l16) * ASTR + ks * 32 + quad * 8;
            short8 ah = *(const short8*)(Ah + ao);
            short8 al = *(const short8*)(Al + ao);
            #pragma unroll
            for (int nt = 0; nt < 2; ++nt) {
                acc[mt][nt] = __builtin_amdgcn_mfma_f32_16x16x32_bf16(ah, bh[nt], acc[mt][nt], 0, 0, 0);
                acc[mt][nt] = __builtin_amdgcn_mfma_f32_16x16x32_bf16(ah, bl[nt], acc[mt][nt], 0, 0, 0);
                acc[mt][nt] = __builtin_amdgcn_mfma_f32_16x16x32_bf16(al, bh[nt], acc[mt][nt], 0, 0, 0);
            }
        }
    }
}

// cross-wave row-LN: pre[4][2][4] per lane; leaves mu in sSum[0..63], rs in sSS[0..63]
static __device__ __forceinline__ void ln_reduce(
    float pre[4][2][4], float* sSum, float* sSS, int w, int l16, int quad, int tid)
{
    #pragma unroll
    for (int mt = 0; mt < 4; ++mt)
        #pragma unroll
        for (int r = 0; r < 4; ++r) {
            float s  = pre[mt][0][r] + pre[mt][1][r];
            float ss = pre[mt][0][r] * pre[mt][0][r] + pre[mt][1][r] * pre[mt][1][r];
            #pragma unroll
            for (int off = 1; off < 16; off <<= 1) {
                s  += __shfl_xor(s, off);
                ss += __shfl_xor(ss, off);
            }
            if (l16 == 0) {
                int row = mt * 16 + quad * 4 + r;
                sSum[w * 64 + row] = s;
                sSS [w * 64 + row] = ss;
            }
        }
    __syncthreads();
    if (tid < 64) {
        float S = 0.f, SS2 = 0.f;
        #pragma unroll
        for (int ww = 0; ww < 8; ++ww) { S += sSum[ww * 64 + tid]; SS2 += sSS[ww * 64 + tid]; }
        float mu = S * (1.f / 256.f);
        float rs = rsqrtf(SS2 * (1.f / 256.f) - mu * mu + EPS);
        sSum[tid] = mu; sSS[tid] = rs;
    }
    __syncthreads();
}

// ---------------------------------------------------------------------------
// Fused edge pipeline, M=64 rows/block, 512 threads (8 waves), bf16x3 MFMA.
__global__ __launch_bounds__(512, 2) void y_mega(
    const float* __restrict__ y, const float* __restrict__ qg, const float* __restrict__ kg,
    const unsigned short* __restrict__ WeH, const unsigned short* __restrict__ WeL,
    const float* __restrict__ be,
    const unsigned short* __restrict__ WoH, const unsigned short* __restrict__ WoL,
    const float* __restrict__ boe,
    const unsigned short* __restrict__ W1H, const unsigned short* __restrict__ W1L,
    const float* __restrict__ b1,
    const unsigned short* __restrict__ W2H, const unsigned short* __restrict__ W2L,
    const float* __restrict__ b2,
    const float* __restrict__ ln4s, const float* __restrict__ ln4b,
    const float* __restrict__ ln6s, const float* __restrict__ ln6b,
    unsigned short* __restrict__ attn_bf, float* __restrict__ yout)
{
    __shared__ unsigned short sAh[MROWS * ASTR], sAl[MROWS * ASTR];   // set1
    __shared__ unsigned short sHh[MROWS * ASTR], sHl[MROWS * ASTR];   // set2 (h quarter)
    __shared__ float sSum[8 * 64], sSS[8 * 64];

    const int tid  = threadIdx.x;
    const int w    = tid >> 6, lane = tid & 63;
    const int l16  = lane & 15, quad = lane >> 4;
    const long long row0 = (long long)blockIdx.x * MROWS;
    const int b  = (int)(row0 >> 14);
    const int i  = (int)((row0 >> 7) & 127);
    const int j0 = (int)(row0 & 127);
    const float* qrow  = qg + ((b << 7) + i) * CDIM;
    const float* kbase = kg + ((b << 7) + j0) * CDIM;
    const int c0 = w * 32 + l16, c1 = c0 + 16;

    // ---- build A1 = y hi/lo planes ----------------------------------------
    {
        int r  = tid >> 3;                  // 64 rows, 8 threads/row
        int cc = (tid & 7) * 32;
        const float* src = y + (row0 + r) * CDIM + cc;
        unsigned short hbuf[32], lbuf[32];
        #pragma unroll
        for (int e = 0; e < 32; e += 4) {
            float4 vv = *(const float4*)(src + e);
            float a[4] = {vv.x, vv.y, vv.z, vv.w};
            #pragma unroll
            for (int d = 0; d < 4; ++d) {
                unsigned short h = f2bf(a[d]);
                hbuf[e + d] = h;
                lbuf[e + d] = f2bf(a[d] - bf2f(h));
            }
        }
        #pragma unroll
        for (int e = 0; e < 32; e += 8) {
            *(short8*)&sAh[r * ASTR + cc + e] = *(short8*)&hbuf[e];
            *(short8*)&sAl[r * ASTR + cc + e] = *(short8*)&lbuf[e];
        }
    }
    __syncthreads();

    f32x4 acc[4][2];
    const f32x4 zf = {0.f, 0.f, 0.f, 0.f};

    // ---- GEMM1: e = y@We + be ---------------------------------------------
    #pragma unroll
    for (int mt = 0; mt < 4; ++mt) { acc[mt][0] = zf; acc[mt][1] = zf; }
    gemm16(sAh, sAl, WeH, WeL, w * 2, 8, 0, lane, acc);

    float q0 = qrow[c0], q1 = qrow[c1];
    float be0 = be[c0], be1 = be[c1];
    float attnv[4][2][4];
    #pragma unroll
    for (int mt = 0; mt < 4; ++mt)
        #pragma unroll
        for (int r = 0; r < 4; ++r) {
            int mloc = mt * 16 + quad * 4 + r;
            float k0 = kbase[mloc * CDIM + c0], k1 = kbase[mloc * CDIM + c1];
            float e0 = acc[mt][0][r] + be0, e1 = acc[mt][1][r] + be1;
            float a0 = q0 * k0 * SCALE * ((e0 + 1.f) * e0);
            float a1 = q1 * k1 * SCALE * ((e1 + 1.f) * e1);
            attnv[mt][0][r] = a0; attnv[mt][1][r] = a1;
            attn_bf[(row0 + mloc) * CDIM + c0] = f2bf(a0);
            attn_bf[(row0 + mloc) * CDIM + c1] = f2bf(a1);
        }
    __syncthreads();                       // all waves done reading set1 (y)

    // scatter attn -> set1 (A for GEMM2)
    #pragma unroll
    for (int mt = 0; mt < 4; ++mt)
        #pragma unroll
        for (int r = 0; r < 4; ++r) {
            int mloc = mt * 16 + quad * 4 + r;
            #pragma unroll
            for (int nt = 0; nt < 2; ++nt) {
                int c = (nt == 0) ? c0 : c1;
                float a = attnv[mt][nt][r];
                unsigned short h = f2bf(a);
                sAh[mloc * ASTR + c] = h;
                sAl[mloc * ASTR + c] = f2bf(a - bf2f(h));
            }
        }
    __syncthreads();

    // ---- GEMM2: edge = attn@Woe + boe ; y2 = LN4(edge + y) ----------------
    #pragma unroll
    for (int mt = 0; mt < 4; ++mt) { acc[mt][0] = zf; acc[mt][1] = zf; }
    gemm16(sAh, sAl, WoH, WoL, w * 2, 8, 0, lane, acc);

    float pre[4][2][4];
    float bo0 = boe[c0], bo1 = boe[c1];
    #pragma unroll
    for (int mt = 0; mt < 4; ++mt)
        #pragma unroll
        for (int r = 0; r < 4; ++r) {
            int mloc = mt * 16 + quad * 4 + r;
            pre[mt][0][r] = acc[mt][0][r] + bo0 + y[(row0 + mloc) * CDIM + c0];
            pre[mt][1][r] = acc[mt][1][r] + bo1 + y[(row0 + mloc) * CDIM + c1];
        }
    ln_reduce(pre, sSum, sSS, w, l16, quad, tid);   // (also fences GEMM2 reads of set1)

    float l4s0 = ln4s[c0], l4b0 = ln4b[c0], l4s1 = ln4s[c1], l4b1 = ln4b[c1];
    float y2v[4][2][4];
    #pragma unroll
    for (int mt = 0; mt < 4; ++mt)
        #pragma unroll
        for (int r = 0; r < 4; ++r) {
            int mloc = mt * 16 + quad * 4 + r;
            float mu = sSum[mloc], rs = sSS[mloc];
            float v0 = (pre[mt][0][r] - mu) * rs * l4s0 + l4b0;
            float v1 = (pre[mt][1][r] - mu) * rs * l4s1 + l4b1;
            y2v[mt][0][r] = v0; y2v[mt][1][r] = v1;
            unsigned short h0 = f2bf(v0), h1 = f2bf(v1);
            sAh[mloc * ASTR + c0] = h0; sAl[mloc * ASTR + c0] = f2bf(v0 - bf2f(h0));
            sAh[mloc * ASTR + c1] = h1; sAl[mloc * ASTR + c1] = f2bf(v1 - bf2f(h1));
        }
    __syncthreads();                       // set1 now holds y2 planes

    // ---- MLP: 4 quarters of 256 hidden units ------------------------------
    f32x4 out[4][2];
    #pragma unroll
    for (int mt = 0; mt < 4; ++mt) { out[mt][0] = zf; out[mt][1] = zf; }
    for (int qq = 0; qq < 4; ++qq) {
        f32x4 hh[4][2];
        #pragma unroll
        for (int mt = 0; mt < 4; ++mt) { hh[mt][0] = zf; hh[mt][1] = zf; }
        gemm16(sAh, sAl, W1H, W1L, qq * 16 + w * 2, 8, 0, lane, hh);
        float bb0 = b1[qq * 256 + c0], bb1 = b1[qq * 256 + c1];
        __syncthreads();                   // previous fc2 done reading set2
        #pragma unroll
        for (int mt = 0; mt < 4; ++mt)
            #pragma unroll
            for (int r = 0; r < 4; ++r) {
                int mloc = mt * 16 + quad * 4 + r;
                float h0 = fmaxf(hh[mt][0][r] + bb0, 0.f);
                float h1 = fmaxf(hh[mt][1][r] + bb1, 0.f);
                unsigned short hb0 = f2bf(h0), hb1 = f2bf(h1);
                sHh[mloc * ASTR + c0] = hb0; sHl[mloc * ASTR + c0] = f2bf(h0 - bf2f(hb0));
                sHh[mloc * ASTR + c1] = hb1; sHl[mloc * ASTR + c1] = f2bf(h1 - bf2f(hb1));
            }
        __syncthreads();
        gemm16(sHh, sHl, W2H, W2L, w * 2, 32, qq * 8, lane, out);
    }

    // ---- epilogue: y_out = LN6(y2 + mlp_out) ------------------------------
    float b20 = b2[c0], b21 = b2[c1];
    #pragma unroll
    for (int mt = 0; mt < 4; ++mt)
        #pragma unroll
        for (int r = 0; r < 4; ++r) {
            pre[mt][0][r] = y2v[mt][0][r] + out[mt][0][r] + b20;
            pre[mt][1][r] = y2v[mt][1][r] + out[mt][1][r] + b21;
        }
    __syncthreads();                       // all fc2 reads of set2 done; sSum reusable
    ln_reduce(pre, sSum, sSS, w, l16, quad, tid);

    float l6s0 = ln6s[c0], l6b0 = ln6b[c0], l6s1 = ln6s[c1], l6b1 = ln6b[c1];
    #pragma unroll
    for (int mt = 0; mt < 4; ++mt)
        #pragma unroll
        for (int r = 0; r < 4; ++r) {
            int mloc = mt * 16 + quad * 4 + r;
            float mu = sSum[mloc], rs = sSS[mloc];
            yout[(row0 + mloc) * CDIM + c0] = (pre[mt][0][r] - mu) * rs * l6s0 + l6b0;
            yout[(row0 + mloc) * CDIM + c1] = (pre[mt][1][r] - mu) * rs * l6s1 + l6b1;
        }
}

// ---------------------------------------------------------------------------
__global__ __launch_bounds__(256) void softmax_agg(
    const unsigned short* __restrict__ attn, const float* __restrict__ v,
    float* __restrict__ agg) {
    const int bi = blockIdx.x, t = threadIdx.x;
    const unsigned short* ap = attn + (long long)bi * NSEQ * CDIM + t;
    const float* vp = v + (long long)(bi >> 7) * NSEQ * CDIM + t;
    float m = -1e30f;
    for (int j = 0; j < NSEQ; ++j) m = fmaxf(m, bf2f(ap[j * CDIM]));
    float s = 0.f, o = 0.f;
    for (int j = 0; j < NSEQ; ++j) {
        float ex = __expf(bf2f(ap[j * CDIM]) - m);
        s += ex;
        o += ex * vp[j * CDIM];
    }
    agg[bi * CDIM + t] = o / s;
}

// ---------------------------------------------------------------------------
__global__ __launch_bounds__(256) void x_path(
    const float* __restrict__ x1, const float* __restrict__ agg,
    const float* __restrict__ Won, const float* __restrict__ bon,
    const float* __restrict__ ln3s, const float* __restrict__ ln3b,
    const float* __restrict__ w1, const float* __restrict__ b1,
    const float* __restrict__ w2, const float* __restrict__ b2,
    const float* __restrict__ ln5s, const float* __restrict__ ln5b,
    float* __restrict__ xout) {
    __shared__ float sG[CDIM];
    __shared__ float sX2[CDIM];
    __shared__ float sH[HID];
    __shared__ float sred[8];
    const int bi = blockIdx.x, t = threadIdx.x;
    sG[t] = agg[bi * CDIM + t];
    __syncthreads();
    float no = bon[t];
    for (int kk = 0; kk < CDIM; kk += 4) {
        float4 gv = *(const float4*)&sG[kk];
        no += gv.x * Won[(kk + 0) * CDIM + t] + gv.y * Won[(kk + 1) * CDIM + t]
            + gv.z * Won[(kk + 2) * CDIM + t] + gv.w * Won[(kk + 3) * CDIM + t];
    }
    float pre = x1[bi * CDIM + t] + no;
    float2 mr = block_ln(pre, sred);
    float x2 = (pre - mr.x) * mr.y * ln3s[t] + ln3b[t];
    sX2[t] = x2;
    __syncthreads();
    float h[4];
    #pragma unroll
    for (int m = 0; m < 4; ++m) h[m] = b1[t + 256 * m];
    for (int kk = 0; kk < CDIM; kk += 4) {
        float4 xv = *(const float4*)&sX2[kk];
        #pragma unroll
        for (int m = 0; m < 4; ++m) {
            int u = t + 256 * m;
            h[m] += xv.x * w1[(kk + 0) * HID + u] + xv.y * w1[(kk + 1) * HID + u]
                  + xv.z * w1[(kk + 2) * HID + u] + xv.w * w1[(kk + 3) * HID + u];
        }
    }
    #pragma unroll
    for (int m = 0; m < 4; ++m) sH[t + 256 * m] = fmaxf(h[m], 0.f);
    __syncthreads();
    float o = b2[t];
    for (int u = 0; u < HID; u += 4) {
        float4 hv = *(const float4*)&sH[u];
        o += hv.x * w2[(u + 0) * CDIM + t] + hv.y * w2[(u + 1) * CDIM + t]
           + hv.z * w2[(u + 2) * CDIM + t] + hv.w * w2[(u + 3) * CDIM + t];
    }
    float pre2 = x2 + o;
    float2 mr2 = block_ln(pre2, sred);
    xout[bi * CDIM + t] = (pre2 - mr2.x) * mr2.y * ln5s[t] + ln5b[t];
}

// ---------------------------------------------------------------------------
extern "C" void kernel_launch(void* const* d_in, const int* in_sizes, int n_in,
                              void* d_out, int out_size, void* d_ws, size_t ws_size,
                              hipStream_t stream) {
    const float* x   = (const float*)d_in[0];
    const float* y   = (const float*)d_in[1];
    const float* Wq  = (const float*)d_in[2];  const float* bq  = (const float*)d_in[3];
    const float* Wk  = (const float*)d_in[4];  const float* bk  = (const float*)d_in[5];
    const float* Wv  = (const float*)d_in[6];  const float* bv  = (const float*)d_in[7];
    const float* We  = (const float*)d_in[8];  const float* be  = (const float*)d_in[9];
    const float* Woe = (const float*)d_in[10]; const float* boe = (const float*)d_in[11];
    const float* Won = (const float*)d_in[12]; const float* bon = (const float*)d_in[13];
    const float* m1w1= (const float*)d_in[14]; const float* m1b1= (const float*)d_in[15];
    const float* m1w2= (const float*)d_in[16]; const float* m1b2= (const float*)d_in[17];
    const float* m2w1= (const float*)d_in[18]; const float* m2b1= (const float*)d_in[19];
    const float* m2w2= (const float*)d_in[20]; const float* m2b2= (const float*)d_in[21];
    const float* ln1s= (const float*)d_in[22]; const float* ln1b= (const float*)d_in[23];
    const float* ln3s= (const float*)d_in[24]; const float* ln3b= (const float*)d_in[25];
    const float* ln4s= (const float*)d_in[26]; const float* ln4b= (const float*)d_in[27];
    const float* ln5s= (const float*)d_in[28]; const float* ln5b= (const float*)d_in[29];
    const float* ln6s= (const float*)d_in[30]; const float* ln6b= (const float*)d_in[31];

    const int BN  = 8 * 128;                 // 1024 node rows
    const long long BNN = 8LL * 128 * 128;   // 131072 edge rows

    float* ws  = (float*)d_ws;
    float* x1  = ws;
    float* q   = x1 + BN * CDIM;
    float* k   = q  + BN * CDIM;
    float* v   = k  + BN * CDIM;
    float* agg = v  + BN * CDIM;
    unsigned short* attn_bf = (unsigned short*)(agg + BN * CDIM);      // 33.5M bf16
    unsigned short* WeH = attn_bf + BNN * CDIM;
    unsigned short* WeL = WeH + 65536;
    unsigned short* WoH = WeL + 65536;
    unsigned short* WoL = WoH + 65536;
    unsigned short* W1H = WoL + 65536;
    unsigned short* W1L = W1H + 262144;
    unsigned short* W2H = W1L + 262144;
    unsigned short* W2L = W2H + 262144;

    float* xout = (float*)d_out;
    float* yout = xout + BN * CDIM;

    prep_w<<<256,  256, 0, stream>>>(We,   WeH, WeL, 256,  3);
    prep_w<<<256,  256, 0, stream>>>(Woe,  WoH, WoL, 256,  3);
    prep_w<<<1024, 256, 0, stream>>>(m2w1, W1H, W1L, 1024, 3);
    prep_w<<<1024, 256, 0, stream>>>(m2w2, W2H, W2L, 256,  5);

    ln1_kernel<<<BN, 256, 0, stream>>>(x, ln1s, ln1b, x1);
    qkv_kernel<<<BN, 256, 0, stream>>>(x1, Wq, bq, Wk, bk, Wv, bv, q, k, v);

    y_mega<<<(int)(BNN / MROWS), 512, 0, stream>>>(
        y, q, k, WeH, WeL, be, WoH, WoL, boe,
        W1H, W1L, m2b1, W2H, W2L, m2b2,
        ln4s, ln4b, ln6s, ln6b, attn_bf, yout);

    softmax_agg<<<BN, 256, 0, stream>>>(attn_bf, v, agg);
    x_path<<<BN, 256, 0, stream>>>(x1, agg, Won, bon, ln3s, ln3b,
                                   m1w1, m1b1, m1w2, m1b2, ln5s, ln5b, xout);
}

// Round 3
// 872.668 us; speedup vs baseline: 4.5514x; 1.1366x over previous
//
#include <hip/hip_runtime.h>

#define CDIM 256
#define NSEQ 128
#define HID 1024
#define EPS 1e-5f
#define SCALE 0.17677669529663687f   // 1/sqrt(32)
#define ASTR 264                     // LDS A-plane row stride (shorts)
#define MROWS 32

typedef __attribute__((ext_vector_type(8))) short short8;
typedef __attribute__((ext_vector_type(4))) float f32x4;

static __device__ __forceinline__ unsigned short f2bf(float x) {
    unsigned u = __float_as_uint(x);
    u += 0x7fff + ((u >> 16) & 1);          // RNE
    return (unsigned short)(u >> 16);
}
static __device__ __forceinline__ float bf2f(unsigned short h) {
    return __uint_as_float(((unsigned)h) << 16);
}

// ---------------------------------------------------------------------------
// One launch: split/swizzle all 4 y-path weights into MFMA B-fragment order.
// out[((nt*(K/32)+ks)*64+lane)*8+j] = W[ks*32+(lane>>4)*8+j][nt*16+(lane&15)]
__global__ __launch_bounds__(256) void prep_all(
    const float* __restrict__ We, const float* __restrict__ Woe,
    const float* __restrict__ W1, const float* __restrict__ W2,
    unsigned short* __restrict__ WeH, unsigned short* __restrict__ WeL,
    unsigned short* __restrict__ WoH, unsigned short* __restrict__ W1H,
    unsigned short* __restrict__ W2H) {
    int blk = blockIdx.x;
    const float* W; unsigned short* H; unsigned short* L = nullptr;
    int N, ksBits, base;
    if (blk < 256)       { W = We;  H = WeH; L = WeL; N = 256;  ksBits = 3; base = 0; }
    else if (blk < 512)  { W = Woe; H = WoH; N = 256;  ksBits = 3; base = 256; }
    else if (blk < 1536) { W = W1;  H = W1H; N = 1024; ksBits = 3; base = 512; }
    else                 { W = W2;  H = W2H; N = 256;  ksBits = 5; base = 1536; }
    int idx = (blk - base) * 256 + threadIdx.x;
    int j = idx & 7, lane = (idx >> 3) & 63, rest = idx >> 9;
    int ks = rest & ((1 << ksBits) - 1), nt = rest >> ksBits;
    int n  = nt * 16 + (lane & 15);
    int kk = ks * 32 + ((lane >> 4) << 3) + j;
    float x = W[kk * N + n];
    unsigned short h = f2bf(x);
    H[idx] = h;
    if (L) L[idx] = f2bf(x - bf2f(h));
}

// ---------------------------------------------------------------------------
// Fused LN1 + qkv, 4 rows per block (weight values reused across 4 rows).
__global__ __launch_bounds__(256) void lnqkv_kernel(
    const float* __restrict__ x,
    const float* __restrict__ ln1s, const float* __restrict__ ln1b,
    const float* __restrict__ Wq, const float* __restrict__ bq,
    const float* __restrict__ Wk, const float* __restrict__ bk,
    const float* __restrict__ Wv, const float* __restrict__ bv,
    float* __restrict__ x1,
    float* __restrict__ q, float* __restrict__ k, float* __restrict__ v) {
    __shared__ float sX[4][CDIM];
    __shared__ float sMu[4], sRs[4];
    const int bi0 = blockIdx.x * 4, t = threadIdx.x;
    const int w = t >> 6, lane = t & 63;
    float xv[4];
    #pragma unroll
    for (int r = 0; r < 4; ++r) { xv[r] = x[(bi0 + r) * CDIM + t]; sX[r][t] = xv[r]; }
    __syncthreads();
    {   // wave w does LN stats for row w
        float s = 0.f, ss = 0.f;
        #pragma unroll
        for (int m = 0; m < 4; ++m) { float a = sX[w][lane + 64 * m]; s += a; ss += a * a; }
        #pragma unroll
        for (int off = 32; off; off >>= 1) { s += __shfl_xor(s, off); ss += __shfl_xor(ss, off); }
        if (lane == 0) {
            float mu = s * (1.f / 256.f);
            sMu[w] = mu;
            sRs[w] = rsqrtf(ss * (1.f / 256.f) - mu * mu + EPS);
        }
    }
    __syncthreads();
    #pragma unroll
    for (int r = 0; r < 4; ++r) {
        float xn = (xv[r] - sMu[r]) * sRs[r] * ln1s[t] + ln1b[t];
        sX[r][t] = xn;
        x1[(bi0 + r) * CDIM + t] = xn;
    }
    __syncthreads();
    float aq[4], ak[4], av[4];
    #pragma unroll
    for (int r = 0; r < 4; ++r) { aq[r] = bq[t]; ak[r] = bk[t]; av[r] = bv[t]; }
    #pragma unroll 4
    for (int kk = 0; kk < CDIM; ++kk) {
        float wq = Wq[kk * CDIM + t], wk = Wk[kk * CDIM + t], wv = Wv[kk * CDIM + t];
        #pragma unroll
        for (int r = 0; r < 4; ++r) {
            float xd = sX[r][kk];
            aq[r] += xd * wq; ak[r] += xd * wk; av[r] += xd * wv;
        }
    }
    #pragma unroll
    for (int r = 0; r < 4; ++r) {
        q[(bi0 + r) * CDIM + t] = aq[r];
        k[(bi0 + r) * CDIM + t] = ak[r];
        v[(bi0 + r) * CDIM + t] = av[r];
    }
}

// ---------------------------------------------------------------------------
// bf16 split GEMM step over K=256: acc[mt][nt] += A*B.
// TERMS==3: Ah*Bh + Al*Bh + Ah*Bl ; TERMS==2: Ah*Bh + Al*Bh (B hi only).
template <int TERMS>
static __device__ __forceinline__ void gemmN(
    const unsigned short* Ah, const unsigned short* Al,
    const unsigned short* __restrict__ Bh, const unsigned short* __restrict__ Bl,
    int nt0, int ksTotal, int ks0, int lane, f32x4 acc[2][2])
{
    const int l16 = lane & 15, quad = lane >> 4;
    #pragma unroll 2
    for (int ks = 0; ks < 8; ++ks) {
        short8 bh[2], bl[2];
        #pragma unroll
        for (int nt = 0; nt < 2; ++nt) {
            size_t off = ((size_t)((nt0 + nt) * ksTotal + (ks0 + ks)) * 64 + lane) * 8;
            bh[nt] = *(const short8*)(Bh + off);
            if (TERMS == 3) bl[nt] = *(const short8*)(Bl + off);
        }
        #pragma unroll
        for (int mt = 0; mt < 2; ++mt) {
            int ao = (mt * 16 + l16) * ASTR + ks * 32 + quad * 8;
            short8 ah = *(const short8*)(Ah + ao);
            short8 al = *(const short8*)(Al + ao);
            #pragma unroll
            for (int nt = 0; nt < 2; ++nt) {
                acc[mt][nt] = __builtin_amdgcn_mfma_f32_16x16x32_bf16(ah, bh[nt], acc[mt][nt], 0, 0, 0);
                acc[mt][nt] = __builtin_amdgcn_mfma_f32_16x16x32_bf16(al, bh[nt], acc[mt][nt], 0, 0, 0);
                if (TERMS == 3)
                    acc[mt][nt] = __builtin_amdgcn_mfma_f32_16x16x32_bf16(ah, bl[nt], acc[mt][nt], 0, 0, 0);
            }
        }
    }
}

// cross-wave row-LN for 32 rows; leaves mu in sSum[0..31], rs in sSS[0..31]
static __device__ __forceinline__ void ln_reduce32(
    float pre[2][2][4], float* sSum, float* sSS, int w, int l16, int quad, int tid)
{
    #pragma unroll
    for (int mt = 0; mt < 2; ++mt)
        #pragma unroll
        for (int r = 0; r < 4; ++r) {
            float s  = pre[mt][0][r] + pre[mt][1][r];
            float ss = pre[mt][0][r] * pre[mt][0][r] + pre[mt][1][r] * pre[mt][1][r];
            #pragma unroll
            for (int off = 1; off < 16; off <<= 1) {
                s  += __shfl_xor(s, off);
                ss += __shfl_xor(ss, off);
            }
            if (l16 == 0) {
                int row = mt * 16 + quad * 4 + r;
                sSum[w * 32 + row] = s;
                sSS [w * 32 + row] = ss;
            }
        }
    __syncthreads();
    if (tid < 32) {
        float S = 0.f, SS2 = 0.f;
        #pragma unroll
        for (int ww = 0; ww < 8; ++ww) { S += sSum[ww * 32 + tid]; SS2 += sSS[ww * 32 + tid]; }
        float mu = S * (1.f / 256.f);
        float rs = rsqrtf(SS2 * (1.f / 256.f) - mu * mu + EPS);
        sSum[tid] = mu; sSS[tid] = rs;
    }
    __syncthreads();
}

// ---------------------------------------------------------------------------
// Fused edge pipeline, M=32 rows/block, 512 threads (8 waves), ~70 KB LDS
// -> 2 blocks/CU so MFMA of one block overlaps VALU/LN phases of the other.
__global__ __launch_bounds__(512, 4) void y_mega(
    const float* __restrict__ y, const float* __restrict__ qg, const float* __restrict__ kg,
    const unsigned short* __restrict__ WeH, const unsigned short* __restrict__ WeL,
    const float* __restrict__ be,
    const unsigned short* __restrict__ WoH, const float* __restrict__ boe,
    const unsigned short* __restrict__ W1H, const float* __restrict__ b1,
    const unsigned short* __restrict__ W2H, const float* __restrict__ b2,
    const float* __restrict__ ln4s, const float* __restrict__ ln4b,
    const float* __restrict__ ln6s, const float* __restrict__ ln6b,
    unsigned short* __restrict__ attn_bf, float* __restrict__ yout)
{
    __shared__ unsigned short sAh[MROWS * ASTR], sAl[MROWS * ASTR];
    __shared__ unsigned short sHh[MROWS * ASTR], sHl[MROWS * ASTR];
    __shared__ float sSum[8 * 32], sSS[8 * 32];

    const int tid  = threadIdx.x;
    const int w    = tid >> 6, lane = tid & 63;
    const int l16  = lane & 15, quad = lane >> 4;
    const long long row0 = (long long)blockIdx.x * MROWS;
    const int b  = (int)(row0 >> 14);
    const int i  = (int)((row0 >> 7) & 127);
    const int j0 = (int)(row0 & 127);
    const float* qrow  = qg + ((b << 7) + i) * CDIM;
    const float* kbase = kg + ((b << 7) + j0) * CDIM;
    const int c0 = w * 32 + l16, c1 = c0 + 16;

    // ---- stage y tile as hi/lo bf16 planes --------------------------------
    {
        int r  = tid >> 4;                  // 32 rows, 16 threads/row
        int cc = (tid & 15) * 16;
        const float* src = y + (row0 + r) * CDIM + cc;
        unsigned short hbuf[16], lbuf[16];
        #pragma unroll
        for (int e = 0; e < 16; e += 4) {
            float4 vv = *(const float4*)(src + e);
            float a[4] = {vv.x, vv.y, vv.z, vv.w};
            #pragma unroll
            for (int d = 0; d < 4; ++d) {
                unsigned short h = f2bf(a[d]);
                hbuf[e + d] = h;
                lbuf[e + d] = f2bf(a[d] - bf2f(h));
            }
        }
        #pragma unroll
        for (int e = 0; e < 16; e += 8) {
            *(short8*)&sAh[r * ASTR + cc + e] = *(short8*)&hbuf[e];
            *(short8*)&sAl[r * ASTR + cc + e] = *(short8*)&lbuf[e];
        }
    }
    __syncthreads();

    f32x4 acc[2][2];
    const f32x4 zf = {0.f, 0.f, 0.f, 0.f};

    // ---- GEMM1 (3-term): e = y@We + be ------------------------------------
    #pragma unroll
    for (int mt = 0; mt < 2; ++mt) { acc[mt][0] = zf; acc[mt][1] = zf; }
    gemmN<3>(sAh, sAl, WeH, WeL, w * 2, 8, 0, lane, acc);

    float q0 = qrow[c0], q1 = qrow[c1];
    float be0 = be[c0], be1 = be[c1];
    float attnv[2][2][4];
    #pragma unroll
    for (int mt = 0; mt < 2; ++mt)
        #pragma unroll
        for (int r = 0; r < 4; ++r) {
            int mloc = mt * 16 + quad * 4 + r;
            float k0 = kbase[mloc * CDIM + c0], k1 = kbase[mloc * CDIM + c1];
            float e0 = acc[mt][0][r] + be0, e1 = acc[mt][1][r] + be1;
            float a0 = q0 * k0 * SCALE * ((e0 + 1.f) * e0);
            float a1 = q1 * k1 * SCALE * ((e1 + 1.f) * e1);
            attnv[mt][0][r] = a0; attnv[mt][1][r] = a1;
            attn_bf[(row0 + mloc) * CDIM + c0] = f2bf(a0);
            attn_bf[(row0 + mloc) * CDIM + c1] = f2bf(a1);
        }
    __syncthreads();                       // all waves done reading y planes

    #pragma unroll
    for (int mt = 0; mt < 2; ++mt)
        #pragma unroll
        for (int r = 0; r < 4; ++r) {
            int mloc = mt * 16 + quad * 4 + r;
            #pragma unroll
            for (int nt = 0; nt < 2; ++nt) {
                int c = (nt == 0) ? c0 : c1;
                float a = attnv[mt][nt][r];
                unsigned short h = f2bf(a);
                sAh[mloc * ASTR + c] = h;
                sAl[mloc * ASTR + c] = f2bf(a - bf2f(h));
            }
        }
    __syncthreads();

    // ---- GEMM2 (2-term): edge = attn@Woe + boe ; y2 = LN4(edge + y) -------
    #pragma unroll
    for (int mt = 0; mt < 2; ++mt) { acc[mt][0] = zf; acc[mt][1] = zf; }
    gemmN<2>(sAh, sAl, WoH, nullptr, w * 2, 8, 0, lane, acc);

    float pre[2][2][4];
    float bo0 = boe[c0], bo1 = boe[c1];
    #pragma unroll
    for (int mt = 0; mt < 2; ++mt)
        #pragma unroll
        for (int r = 0; r < 4; ++r) {
            int mloc = mt * 16 + quad * 4 + r;
            pre[mt][0][r] = acc[mt][0][r] + bo0 + y[(row0 + mloc) * CDIM + c0];
            pre[mt][1][r] = acc[mt][1][r] + bo1 + y[(row0 + mloc) * CDIM + c1];
        }
    ln_reduce32(pre, sSum, sSS, w, l16, quad, tid);

    float l4s0 = ln4s[c0], l4b0 = ln4b[c0], l4s1 = ln4s[c1], l4b1 = ln4b[c1];
    float y2v[2][2][4];
    #pragma unroll
    for (int mt = 0; mt < 2; ++mt)
        #pragma unroll
        for (int r = 0; r < 4; ++r) {
            int mloc = mt * 16 + quad * 4 + r;
            float mu = sSum[mloc], rs = sSS[mloc];
            float v0 = (pre[mt][0][r] - mu) * rs * l4s0 + l4b0;
            float v1 = (pre[mt][1][r] - mu) * rs * l4s1 + l4b1;
            y2v[mt][0][r] = v0; y2v[mt][1][r] = v1;
            unsigned short h0 = f2bf(v0), h1 = f2bf(v1);
            sAh[mloc * ASTR + c0] = h0; sAl[mloc * ASTR + c0] = f2bf(v0 - bf2f(h0));
            sAh[mloc * ASTR + c1] = h1; sAl[mloc * ASTR + c1] = f2bf(v1 - bf2f(h1));
        }
    __syncthreads();                       // A planes now hold y2

    // ---- MLP (2-term), 4 quarters of 256 hidden units ---------------------
    f32x4 out[2][2];
    #pragma unroll
    for (int mt = 0; mt < 2; ++mt) { out[mt][0] = zf; out[mt][1] = zf; }
    for (int qq = 0; qq < 4; ++qq) {
        f32x4 hh[2][2];
        #pragma unroll
        for (int mt = 0; mt < 2; ++mt) { hh[mt][0] = zf; hh[mt][1] = zf; }
        gemmN<2>(sAh, sAl, W1H, nullptr, qq * 16 + w * 2, 8, 0, lane, hh);
        float bb0 = b1[qq * 256 + c0], bb1 = b1[qq * 256 + c1];
        __syncthreads();                   // previous fc2 done reading H planes
        #pragma unroll
        for (int mt = 0; mt < 2; ++mt)
            #pragma unroll
            for (int r = 0; r < 4; ++r) {
                int mloc = mt * 16 + quad * 4 + r;
                float h0 = fmaxf(hh[mt][0][r] + bb0, 0.f);
                float h1 = fmaxf(hh[mt][1][r] + bb1, 0.f);
                unsigned short hb0 = f2bf(h0), hb1 = f2bf(h1);
                sHh[mloc * ASTR + c0] = hb0; sHl[mloc * ASTR + c0] = f2bf(h0 - bf2f(hb0));
                sHh[mloc * ASTR + c1] = hb1; sHl[mloc * ASTR + c1] = f2bf(h1 - bf2f(hb1));
            }
        __syncthreads();
        gemmN<2>(sHh, sHl, W2H, nullptr, w * 2, 32, qq * 8, lane, out);
    }

    // ---- epilogue: y_out = LN6(y2 + mlp_out + b2) -------------------------
    float b20 = b2[c0], b21 = b2[c1];
    #pragma unroll
    for (int mt = 0; mt < 2; ++mt)
        #pragma unroll
        for (int r = 0; r < 4; ++r) {
            pre[mt][0][r] = y2v[mt][0][r] + out[mt][0][r] + b20;
            pre[mt][1][r] = y2v[mt][1][r] + out[mt][1][r] + b21;
        }
    ln_reduce32(pre, sSum, sSS, w, l16, quad, tid);

    float l6s0 = ln6s[c0], l6b0 = ln6b[c0], l6s1 = ln6s[c1], l6b1 = ln6b[c1];
    #pragma unroll
    for (int mt = 0; mt < 2; ++mt)
        #pragma unroll
        for (int r = 0; r < 4; ++r) {
            int mloc = mt * 16 + quad * 4 + r;
            float mu = sSum[mloc], rs = sSS[mloc];
            yout[(row0 + mloc) * CDIM + c0] = (pre[mt][0][r] - mu) * rs * l6s0 + l6b0;
            yout[(row0 + mloc) * CDIM + c1] = (pre[mt][1][r] - mu) * rs * l6s1 + l6b1;
        }
}

// ---------------------------------------------------------------------------
// softmax over j + weighted v-sum. 2 channels/thread, j-range split in 2 teams.
__global__ __launch_bounds__(256) void softmax_agg(
    const unsigned short* __restrict__ attn, const float* __restrict__ v,
    float* __restrict__ agg) {
    __shared__ float2 sM[2][128], sS[2][128], sO[2][128];
    const int bi = blockIdx.x, t = threadIdx.x;
    const int c2 = t & 127, team = t >> 7, ch = c2 * 2;
    const unsigned short* ap = attn + (size_t)bi * NSEQ * CDIM + ch;
    const float* vp = v + (size_t)(bi >> 7) * NSEQ * CDIM + ch;
    const int jb = team * 64;
    float m0 = -1e30f, m1 = -1e30f;
    #pragma unroll 4
    for (int j = jb; j < jb + 64; ++j) {
        unsigned uu = *(const unsigned*)(ap + (size_t)j * CDIM);
        m0 = fmaxf(m0, bf2f((unsigned short)uu));
        m1 = fmaxf(m1, bf2f((unsigned short)(uu >> 16)));
    }
    sM[team][c2] = make_float2(m0, m1);
    __syncthreads();
    float2 mo = sM[team ^ 1][c2];
    m0 = fmaxf(m0, mo.x); m1 = fmaxf(m1, mo.y);
    float s0 = 0.f, s1 = 0.f, o0 = 0.f, o1 = 0.f;
    #pragma unroll 4
    for (int j = jb; j < jb + 64; ++j) {
        unsigned uu = *(const unsigned*)(ap + (size_t)j * CDIM);
        float e0 = __expf(bf2f((unsigned short)uu) - m0);
        float e1 = __expf(bf2f((unsigned short)(uu >> 16)) - m1);
        float2 vv = *(const float2*)(vp + (size_t)j * CDIM);
        s0 += e0; s1 += e1;
        o0 += e0 * vv.x; o1 += e1 * vv.y;
    }
    sS[team][c2] = make_float2(s0, s1);
    sO[team][c2] = make_float2(o0, o1);
    __syncthreads();
    if (team == 0) {
        float2 s2 = sS[1][c2], o2 = sO[1][c2];
        float r0 = (o0 + o2.x) / (s0 + s2.x);
        float r1 = (o1 + o2.y) / (s1 + s2.y);
        *(float2*)(agg + (size_t)bi * CDIM + ch) = make_float2(r0, r1);
    }
}

// ---------------------------------------------------------------------------
// node path, 4 rows per block (weights reused across rows).
__global__ __launch_bounds__(256) void x_path(
    const float* __restrict__ x1, const float* __restrict__ agg,
    const float* __restrict__ Won, const float* __restrict__ bon,
    const float* __restrict__ ln3s, const float* __restrict__ ln3b,
    const float* __restrict__ w1, const float* __restrict__ b1,
    const float* __restrict__ w2, const float* __restrict__ b2,
    const float* __restrict__ ln5s, const float* __restrict__ ln5b,
    float* __restrict__ xout) {
    __shared__ float sG[4][CDIM];
    __shared__ float sP[4][CDIM];
    __shared__ float sH[4][HID];
    __shared__ float sMu[4], sRs[4];
    const int bi0 = blockIdx.x * 4, t = threadIdx.x;
    const int w = t >> 6, lane = t & 63;
    #pragma unroll
    for (int r = 0; r < 4; ++r) sG[r][t] = agg[(bi0 + r) * CDIM + t];
    __syncthreads();
    float no[4];
    #pragma unroll
    for (int r = 0; r < 4; ++r) no[r] = bon[t];
    #pragma unroll 4
    for (int kk = 0; kk < CDIM; ++kk) {
        float wv = Won[kk * CDIM + t];
        #pragma unroll
        for (int r = 0; r < 4; ++r) no[r] += sG[r][kk] * wv;
    }
    float pre[4];
    #pragma unroll
    for (int r = 0; r < 4; ++r) {
        pre[r] = x1[(bi0 + r) * CDIM + t] + no[r];
        sP[r][t] = pre[r];
    }
    __syncthreads();
    {
        float s = 0.f, ss = 0.f;
        #pragma unroll
        for (int m = 0; m < 4; ++m) { float a = sP[w][lane + 64 * m]; s += a; ss += a * a; }
        #pragma unroll
        for (int off = 32; off; off >>= 1) { s += __shfl_xor(s, off); ss += __shfl_xor(ss, off); }
        if (lane == 0) {
            float mu = s * (1.f / 256.f);
            sMu[w] = mu; sRs[w] = rsqrtf(ss * (1.f / 256.f) - mu * mu + EPS);
        }
    }
    __syncthreads();
    float x2[4];
    #pragma unroll
    for (int r = 0; r < 4; ++r) {
        x2[r] = (pre[r] - sMu[r]) * sRs[r] * ln3s[t] + ln3b[t];
        sP[r][t] = x2[r];
    }
    __syncthreads();
    float h[4][4];
    #pragma unroll
    for (int m = 0; m < 4; ++m) {
        float bb = b1[t + 256 * m];
        #pragma unroll
        for (int r = 0; r < 4; ++r) h[r][m] = bb;
    }
    #pragma unroll 2
    for (int kk = 0; kk < CDIM; ++kk) {
        float wv[4];
        #pragma unroll
        for (int m = 0; m < 4; ++m) wv[m] = w1[kk * HID + t + 256 * m];
        #pragma unroll
        for (int r = 0; r < 4; ++r) {
            float xd = sP[r][kk];
            #pragma unroll
            for (int m = 0; m < 4; ++m) h[r][m] += xd * wv[m];
        }
    }
    #pragma unroll
    for (int r = 0; r < 4; ++r)
        #pragma unroll
        for (int m = 0; m < 4; ++m) sH[r][t + 256 * m] = fmaxf(h[r][m], 0.f);
    __syncthreads();
    float o[4];
    #pragma unroll
    for (int r = 0; r < 4; ++r) o[r] = b2[t];
    #pragma unroll 4
    for (int u = 0; u < HID; ++u) {
        float wv = w2[u * CDIM + t];
        #pragma unroll
        for (int r = 0; r < 4; ++r) o[r] += sH[r][u] * wv;
    }
    float pre2[4];
    #pragma unroll
    for (int r = 0; r < 4; ++r) { pre2[r] = x2[r] + o[r]; sP[r][t] = pre2[r]; }
    __syncthreads();
    {
        float s = 0.f, ss = 0.f;
        #pragma unroll
        for (int m = 0; m < 4; ++m) { float a = sP[w][lane + 64 * m]; s += a; ss += a * a; }
        #pragma unroll
        for (int off = 32; off; off >>= 1) { s += __shfl_xor(s, off); ss += __shfl_xor(ss, off); }
        if (lane == 0) {
            float mu = s * (1.f / 256.f);
            sMu[w] = mu; sRs[w] = rsqrtf(ss * (1.f / 256.f) - mu * mu + EPS);
        }
    }
    __syncthreads();
    #pragma unroll
    for (int r = 0; r < 4; ++r)
        xout[(bi0 + r) * CDIM + t] = (pre2[r] - sMu[r]) * sRs[r] * ln5s[t] + ln5b[t];
}

// ---------------------------------------------------------------------------
extern "C" void kernel_launch(void* const* d_in, const int* in_sizes, int n_in,
                              void* d_out, int out_size, void* d_ws, size_t ws_size,
                              hipStream_t stream) {
    const float* x   = (const float*)d_in[0];
    const float* y   = (const float*)d_in[1];
    const float* Wq  = (const float*)d_in[2];  const float* bq  = (const float*)d_in[3];
    const float* Wk  = (const float*)d_in[4];  const float* bk  = (const float*)d_in[5];
    const float* Wv  = (const float*)d_in[6];  const float* bv  = (const float*)d_in[7];
    const float* We  = (const float*)d_in[8];  const float* be  = (const float*)d_in[9];
    const float* Woe = (const float*)d_in[10]; const float* boe = (const float*)d_in[11];
    const float* Won = (const float*)d_in[12]; const float* bon = (const float*)d_in[13];
    const float* m1w1= (const float*)d_in[14]; const float* m1b1= (const float*)d_in[15];
    const float* m1w2= (const float*)d_in[16]; const float* m1b2= (const float*)d_in[17];
    const float* m2w1= (const float*)d_in[18]; const float* m2b1= (const float*)d_in[19];
    const float* m2w2= (const float*)d_in[20]; const float* m2b2= (const float*)d_in[21];
    const float* ln1s= (const float*)d_in[22]; const float* ln1b= (const float*)d_in[23];
    const float* ln3s= (const float*)d_in[24]; const float* ln3b= (const float*)d_in[25];
    const float* ln4s= (const float*)d_in[26]; const float* ln4b= (const float*)d_in[27];
    const float* ln5s= (const float*)d_in[28]; const float* ln5b= (const float*)d_in[29];
    const float* ln6s= (const float*)d_in[30]; const float* ln6b= (const float*)d_in[31];

    const int BN  = 8 * 128;                 // 1024 node rows
    const long long BNN = 8LL * 128 * 128;   // 131072 edge rows

    float* ws  = (float*)d_ws;
    float* x1  = ws;
    float* q   = x1 + BN * CDIM;
    float* k   = q  + BN * CDIM;
    float* v   = k  + BN * CDIM;
    float* agg = v  + BN * CDIM;
    unsigned short* attn_bf = (unsigned short*)(agg + BN * CDIM);
    unsigned short* WeH = attn_bf + BNN * CDIM;
    unsigned short* WeL = WeH + 65536;
    unsigned short* WoH = WeL + 65536;
    unsigned short* W1H = WoH + 65536;
    unsigned short* W2H = W1H + 262144;

    float* xout = (float*)d_out;
    float* yout = xout + BN * CDIM;

    prep_all<<<2560, 256, 0, stream>>>(We, Woe, m2w1, m2w2, WeH, WeL, WoH, W1H, W2H);
    lnqkv_kernel<<<BN / 4, 256, 0, stream>>>(x, ln1s, ln1b, Wq, bq, Wk, bk, Wv, bv,
                                             x1, q, k, v);
    y_mega<<<(int)(BNN / MROWS), 512, 0, stream>>>(
        y, q, k, WeH, WeL, be, WoH, boe, W1H, m2b1, W2H, m2b2,
        ln4s, ln4b, ln6s, ln6b, attn_bf, yout);
    softmax_agg<<<BN, 256, 0, stream>>>(attn_bf, v, agg);
    x_path<<<BN / 4, 256, 0, stream>>>(x1, agg, Won, bon, ln3s, ln3b,
                                       m1w1, m1b1, m1w2, m1b2, ln5s, ln5b, xout);
}